// Round 1
// baseline (773.993 us; speedup 1.0000x reference)
//
#include <hip/hip_runtime.h>
#include <hip/hip_bf16.h>
#include <cstddef>

// Problem constants
#define B_SZ 16
#define C_IMG 512
#define HW 1024          // 32*32
#define C_AUD 512
#define K_LEN 256
#define N_HEADS 8
#define HEAD_DIM 64
#define EPS 1e-5f

// ---------------------------------------------------------------------------
// GEMM Q: q[b][s][n] = sum_c img[b][c][s] * Wq[c][n] + bq[n]
// A is accessed transposed: contiguous in s (m dimension).
// 64x64 tile, TK=16, block 256 (16x16), 4x4 micro-tile per thread.
// ---------------------------------------------------------------------------
__global__ __launch_bounds__(256) void gemm_q_kernel(
    const float* __restrict__ img,   // [B][512][1024]
    const float* __restrict__ Wq,    // [512][512]
    const float* __restrict__ bq,    // [512]
    float* __restrict__ qout)        // [B][1024][512]
{
    const int b  = blockIdx.z;
    const int m0 = blockIdx.x * 64;   // s
    const int n0 = blockIdx.y * 64;   // out channel
    const int tid = threadIdx.x;
    const int tx = tid & 15, ty = tid >> 4;

    __shared__ float As[16][68];
    __shared__ float Bs[16][68];

    float acc[4][4] = {};
    const float* Ab = img + (size_t)b * C_IMG * HW;

    for (int k0 = 0; k0 < C_IMG; k0 += 16) {
        // Load A tile: As[k][m] = img[b][k0+k][m0+m]  (contiguous in m)
        {
            const int k = tid >> 4;            // 0..15
            const int m = (tid & 15) << 2;     // 0..60
            float4 a = *(const float4*)(Ab + (size_t)(k0 + k) * HW + m0 + m);
            *(float4*)&As[k][m] = a;
            float4 w = *(const float4*)(Wq + (size_t)(k0 + k) * C_AUD + n0 + m);
            *(float4*)&Bs[k][m] = w;
        }
        __syncthreads();
        #pragma unroll
        for (int k = 0; k < 16; ++k) {
            float4 a4 = *(const float4*)&As[k][ty << 2];
            float4 b4 = *(const float4*)&Bs[k][tx << 2];
            float av[4] = {a4.x, a4.y, a4.z, a4.w};
            float bv[4] = {b4.x, b4.y, b4.z, b4.w};
            #pragma unroll
            for (int i = 0; i < 4; ++i)
                #pragma unroll
                for (int j = 0; j < 4; ++j)
                    acc[i][j] += av[i] * bv[j];
        }
        __syncthreads();
    }

    float4 bias = *(const float4*)(bq + n0 + (tx << 2));
    float bb[4] = {bias.x, bias.y, bias.z, bias.w};
    #pragma unroll
    for (int i = 0; i < 4; ++i) {
        float4 r;
        r.x = acc[i][0] + bb[0];
        r.y = acc[i][1] + bb[1];
        r.z = acc[i][2] + bb[2];
        r.w = acc[i][3] + bb[3];
        *(float4*)(qout + ((size_t)b * HW + m0 + (ty << 2) + i) * C_AUD + n0 + (tx << 2)) = r;
    }
}

// ---------------------------------------------------------------------------
// Generic row-major GEMM: C[b][m][n] = sum_k A[b][m][k] * W[k][n] + bias[n]
// Used for K, V (M=256) and output projection (M=1024).
// ---------------------------------------------------------------------------
__global__ __launch_bounds__(256) void gemm_rm_kernel(
    const float* __restrict__ A,     // [B][M][512]
    const float* __restrict__ W,     // [512][512]
    const float* __restrict__ bias,  // [512]
    float* __restrict__ Cout,        // [B][M][512]
    int M)
{
    const int b  = blockIdx.z;
    const int m0 = blockIdx.x * 64;
    const int n0 = blockIdx.y * 64;
    const int tid = threadIdx.x;
    const int tx = tid & 15, ty = tid >> 4;

    __shared__ float As[16][68];
    __shared__ float Bs[16][68];

    float acc[4][4] = {};
    const float* Ab = A + (size_t)b * M * C_AUD;

    for (int k0 = 0; k0 < C_AUD; k0 += 16) {
        // A tile: A[b][m0+mm][k0+kk] contiguous in k -> transpose into As[k][m]
        {
            const int mm  = tid >> 2;          // 0..63
            const int kk4 = (tid & 3) << 2;    // 0,4,8,12
            float4 a = *(const float4*)(Ab + (size_t)(m0 + mm) * C_AUD + k0 + kk4);
            As[kk4 + 0][mm] = a.x;
            As[kk4 + 1][mm] = a.y;
            As[kk4 + 2][mm] = a.z;
            As[kk4 + 3][mm] = a.w;
            const int kb = tid >> 4;
            const int nn = (tid & 15) << 2;
            float4 w = *(const float4*)(W + (size_t)(k0 + kb) * C_AUD + n0 + nn);
            *(float4*)&Bs[kb][nn] = w;
        }
        __syncthreads();
        #pragma unroll
        for (int k = 0; k < 16; ++k) {
            float4 a4 = *(const float4*)&As[k][ty << 2];
            float4 b4 = *(const float4*)&Bs[k][tx << 2];
            float av[4] = {a4.x, a4.y, a4.z, a4.w};
            float bv[4] = {b4.x, b4.y, b4.z, b4.w};
            #pragma unroll
            for (int i = 0; i < 4; ++i)
                #pragma unroll
                for (int j = 0; j < 4; ++j)
                    acc[i][j] += av[i] * bv[j];
        }
        __syncthreads();
    }

    float4 bv4 = *(const float4*)(bias + n0 + (tx << 2));
    float bb[4] = {bv4.x, bv4.y, bv4.z, bv4.w};
    #pragma unroll
    for (int i = 0; i < 4; ++i) {
        float4 r;
        r.x = acc[i][0] + bb[0];
        r.y = acc[i][1] + bb[1];
        r.z = acc[i][2] + bb[2];
        r.w = acc[i][3] + bb[3];
        *(float4*)(Cout + ((size_t)b * M + m0 + (ty << 2) + i) * C_AUD + n0 + (tx << 2)) = r;
    }
}

// ---------------------------------------------------------------------------
// Fused attention: per (b, head, q-tile of 256 rows). One thread = one q row.
// Online softmax over 4 key-tiles of 64 keys staged in LDS.
// ---------------------------------------------------------------------------
__global__ __launch_bounds__(256) void attn_kernel(
    const float* __restrict__ q,   // [B][1024][512]
    const float* __restrict__ k,   // [B][256][512]
    const float* __restrict__ v,   // [B][256][512]
    float* __restrict__ o)         // [B][1024][512]
{
    const int bh = blockIdx.x;        // 0..127
    const int b = bh >> 3, h = bh & 7;
    const int row = blockIdx.y * 256 + threadIdx.x;  // 0..1023
    const int tid = threadIdx.x;

    __shared__ float Ks[64][64];
    __shared__ float Vs[64][64];

    // Load this thread's q row (64 floats)
    float qr[64];
    const float* qp = q + ((size_t)b * HW + row) * C_AUD + h * HEAD_DIM;
    #pragma unroll
    for (int j = 0; j < 16; ++j) {
        float4 t = *(const float4*)(qp + (j << 2));
        qr[4*j+0] = t.x; qr[4*j+1] = t.y; qr[4*j+2] = t.z; qr[4*j+3] = t.w;
    }

    float m_i = -1e30f, l_i = 0.0f;
    float acc[64] = {};

    const float* kb = k + (size_t)b * K_LEN * C_AUD + h * HEAD_DIM;
    const float* vb = v + (size_t)b * K_LEN * C_AUD + h * HEAD_DIM;

    for (int kt = 0; kt < 4; ++kt) {
        __syncthreads();
        // Stage 64x64 K and V tiles (1024 float4 each, 256 threads x 4 iters)
        for (int i = tid; i < 64 * 16; i += 256) {
            const int rr = i >> 4;
            const int dd = (i & 15) << 2;
            const size_t goff = (size_t)(kt * 64 + rr) * C_AUD + dd;
            *(float4*)&Ks[rr][dd] = *(const float4*)(kb + goff);
            *(float4*)&Vs[rr][dd] = *(const float4*)(vb + goff);
        }
        __syncthreads();

        for (int kk = 0; kk < 64; ++kk) {
            const float4* kr = (const float4*)Ks[kk];
            float s = 0.0f;
            #pragma unroll
            for (int j = 0; j < 16; ++j) {
                float4 t = kr[j];
                s += qr[4*j+0]*t.x + qr[4*j+1]*t.y + qr[4*j+2]*t.z + qr[4*j+3]*t.w;
            }
            s *= 0.125f;  // 1/sqrt(64)

            float w;
            if (s > m_i) {
                float a = __expf(m_i - s);
                l_i *= a;
                #pragma unroll
                for (int d = 0; d < 64; ++d) acc[d] *= a;
                m_i = s;
                w = 1.0f;
            } else {
                w = __expf(s - m_i);
            }
            l_i += w;

            const float4* vr = (const float4*)Vs[kk];
            #pragma unroll
            for (int j = 0; j < 16; ++j) {
                float4 t = vr[j];
                acc[4*j+0] += w * t.x;
                acc[4*j+1] += w * t.y;
                acc[4*j+2] += w * t.z;
                acc[4*j+3] += w * t.w;
            }
        }
    }

    const float inv = 1.0f / l_i;
    float* op = o + ((size_t)b * HW + row) * C_AUD + h * HEAD_DIM;
    #pragma unroll
    for (int j = 0; j < 16; ++j) {
        float4 r;
        r.x = acc[4*j+0] * inv;
        r.y = acc[4*j+1] * inv;
        r.z = acc[4*j+2] * inv;
        r.w = acc[4*j+3] * inv;
        *(float4*)(op + (j << 2)) = r;
    }
}

// ---------------------------------------------------------------------------
// Epilogue: y = img_seq + proj; LayerNorm over channels; transpose to [b,c,s]
// One wave (64 lanes) per (b, s) row; 4 waves per block.
// ---------------------------------------------------------------------------
__global__ __launch_bounds__(256) void ln_kernel(
    const float* __restrict__ proj,   // [B][1024][512]
    const float* __restrict__ img,    // [B][512][1024]
    const float* __restrict__ gamma,  // [512]
    const float* __restrict__ beta,   // [512]
    float* __restrict__ out)          // [B][512][1024]
{
    const int wave = threadIdx.x >> 6;
    const int lane = threadIdx.x & 63;
    const int rowg = blockIdx.x * 4 + wave;   // 0..16383
    const int b = rowg >> 10;
    const int s = rowg & 1023;

    const float* pr = proj + (size_t)rowg * C_IMG;
    const float* ib = img + (size_t)b * C_IMG * HW + s;

    float y[8];
    float sum = 0.0f;
    #pragma unroll
    for (int j = 0; j < 8; ++j) {
        const int c = lane + j * 64;
        y[j] = pr[c] + ib[(size_t)c * HW];
        sum += y[j];
    }
    #pragma unroll
    for (int off = 32; off > 0; off >>= 1) sum += __shfl_xor(sum, off, 64);
    const float mu = sum * (1.0f / 512.0f);

    float vs = 0.0f;
    #pragma unroll
    for (int j = 0; j < 8; ++j) {
        const float d = y[j] - mu;
        vs += d * d;
    }
    #pragma unroll
    for (int off = 32; off > 0; off >>= 1) vs += __shfl_xor(vs, off, 64);
    const float rstd = rsqrtf(vs * (1.0f / 512.0f) + EPS);

    float* ob = out + (size_t)b * C_IMG * HW + s;
    #pragma unroll
    for (int j = 0; j < 8; ++j) {
        const int c = lane + j * 64;
        ob[(size_t)c * HW] = (y[j] - mu) * rstd * gamma[c] + beta[c];
    }
}

// ---------------------------------------------------------------------------
extern "C" void kernel_launch(void* const* d_in, const int* in_sizes, int n_in,
                              void* d_out, int out_size, void* d_ws, size_t ws_size,
                              hipStream_t stream) {
    const float* img   = (const float*)d_in[0];
    const float* audio = (const float*)d_in[1];
    const float* Wq    = (const float*)d_in[2];
    const float* bq    = (const float*)d_in[3];
    const float* Wk    = (const float*)d_in[4];
    const float* bk    = (const float*)d_in[5];
    const float* Wv    = (const float*)d_in[6];
    const float* bv    = (const float*)d_in[7];
    const float* Wo    = (const float*)d_in[8];
    const float* bo    = (const float*)d_in[9];
    const float* gamma = (const float*)d_in[10];
    const float* beta  = (const float*)d_in[11];

    float* ws   = (float*)d_ws;
    float* qbuf = ws;                                  // 16*1024*512 = 8388608
    float* kbuf = qbuf + (size_t)B_SZ * HW * C_AUD;    // 2097152
    float* vbuf = kbuf + (size_t)B_SZ * K_LEN * C_AUD;
    float* abuf = vbuf + (size_t)B_SZ * K_LEN * C_AUD; // 8388608
    float* pbuf = qbuf;  // proj aliases q (q dead after attention)

    // Q projection: [16,1024,512]
    gemm_q_kernel<<<dim3(HW / 64, C_AUD / 64, B_SZ), 256, 0, stream>>>(img, Wq, bq, qbuf);
    // K, V projections: [16,256,512]
    gemm_rm_kernel<<<dim3(K_LEN / 64, C_AUD / 64, B_SZ), 256, 0, stream>>>(audio, Wk, bk, kbuf, K_LEN);
    gemm_rm_kernel<<<dim3(K_LEN / 64, C_AUD / 64, B_SZ), 256, 0, stream>>>(audio, Wv, bv, vbuf, K_LEN);
    // Fused attention
    attn_kernel<<<dim3(B_SZ * N_HEADS, HW / 256), 256, 0, stream>>>(qbuf, kbuf, vbuf, abuf);
    // Output projection
    gemm_rm_kernel<<<dim3(HW / 64, C_AUD / 64, B_SZ), 256, 0, stream>>>(abuf, Wo, bo, pbuf, HW);
    // Residual + LayerNorm + transpose
    ln_kernel<<<dim3(B_SZ * HW / 4), 256, 0, stream>>>(pbuf, img, gamma, beta, (float*)d_out);
}

// Round 2
// 399.570 us; speedup vs baseline: 1.9371x; 1.9371x over previous
//
#include <hip/hip_runtime.h>
#include <cstddef>

#define B_SZ 16
#define HW 1024
#define CCH 512
#define K_LEN 256
#define N_HEADS 8
#define EPS 1e-5f

typedef __bf16 bf16;
typedef bf16 bf16x8 __attribute__((ext_vector_type(8)));
typedef float f32x4 __attribute__((ext_vector_type(4)));

// ---------------------------------------------------------------------------
// Transpose+cast img: [B][512][1024] f32 -> [B][1024][512] bf16
// ---------------------------------------------------------------------------
__global__ __launch_bounds__(256) void transpose_cast_img(
    const float* __restrict__ src, bf16* __restrict__ dst)
{
    const int b  = blockIdx.z;
    const int s0 = blockIdx.x * 64;   // src col
    const int c0 = blockIdx.y * 64;   // src row
    __shared__ bf16 T[64][72];
    const int tid = threadIdx.x;
    {
        const int r = tid >> 2, cs = (tid & 3) << 4;
        const float* sp = src + ((size_t)b * CCH + c0 + r) * HW + s0 + cs;
        #pragma unroll
        for (int i = 0; i < 4; ++i) {
            float4 f = *(const float4*)(sp + i * 4);
            T[r][cs + i*4 + 0] = (bf16)f.x;
            T[r][cs + i*4 + 1] = (bf16)f.y;
            T[r][cs + i*4 + 2] = (bf16)f.z;
            T[r][cs + i*4 + 3] = (bf16)f.w;
        }
    }
    __syncthreads();
    {
        const int ss = tid >> 2, ks = (tid & 3) << 4;
        bf16x8 a, b8;
        #pragma unroll
        for (int j = 0; j < 8; ++j) { a[j] = T[ks + j][ss]; b8[j] = T[ks + 8 + j][ss]; }
        bf16* dp = dst + ((size_t)b * HW + s0 + ss) * CCH + c0 + ks;
        *(bf16x8*)dp = a;
        *(bf16x8*)(dp + 8) = b8;
    }
}

// ---------------------------------------------------------------------------
// Transpose+cast the 4 weight matrices: W[k][n] f32 -> Wt[n][k] bf16, packed
// dst layout: [4][512][512] in order q,k,v,o
// ---------------------------------------------------------------------------
__global__ __launch_bounds__(256) void transpose_cast_w(
    const float* __restrict__ Wq, const float* __restrict__ Wk,
    const float* __restrict__ Wv, const float* __restrict__ Wo,
    bf16* __restrict__ dst)
{
    const int w = blockIdx.z;
    const float* src = (w == 0) ? Wq : (w == 1) ? Wk : (w == 2) ? Wv : Wo;
    const int n0 = blockIdx.x * 64;   // src col (n)
    const int k0 = blockIdx.y * 64;   // src row (k)
    __shared__ bf16 T[64][72];
    const int tid = threadIdx.x;
    {
        const int r = tid >> 2, cs = (tid & 3) << 4;
        const float* sp = src + (size_t)(k0 + r) * CCH + n0 + cs;
        #pragma unroll
        for (int i = 0; i < 4; ++i) {
            float4 f = *(const float4*)(sp + i * 4);
            T[r][cs + i*4 + 0] = (bf16)f.x;
            T[r][cs + i*4 + 1] = (bf16)f.y;
            T[r][cs + i*4 + 2] = (bf16)f.z;
            T[r][cs + i*4 + 3] = (bf16)f.w;
        }
    }
    __syncthreads();
    {
        const int nn = tid >> 2, ks = (tid & 3) << 4;
        bf16x8 a, b8;
        #pragma unroll
        for (int j = 0; j < 8; ++j) { a[j] = T[ks + j][nn]; b8[j] = T[ks + 8 + j][nn]; }
        bf16* dp = dst + (size_t)w * CCH * CCH + (size_t)(n0 + nn) * CCH + k0 + ks;
        *(bf16x8*)dp = a;
        *(bf16x8*)(dp + 8) = b8;
    }
}

// ---------------------------------------------------------------------------
// Elementwise cast audio f32 -> bf16 (2097152 elems, 8 per thread)
// ---------------------------------------------------------------------------
__global__ __launch_bounds__(256) void cast_audio(
    const float* __restrict__ src, bf16* __restrict__ dst)
{
    const size_t i = ((size_t)blockIdx.x * 256 + threadIdx.x) * 8;
    float4 a = *(const float4*)(src + i);
    float4 b = *(const float4*)(src + i + 4);
    bf16x8 o;
    o[0] = (bf16)a.x; o[1] = (bf16)a.y; o[2] = (bf16)a.z; o[3] = (bf16)a.w;
    o[4] = (bf16)b.x; o[5] = (bf16)b.y; o[6] = (bf16)b.z; o[7] = (bf16)b.w;
    *(bf16x8*)(dst + i) = o;
}

// ---------------------------------------------------------------------------
// MFMA bf16 GEMM: out[m][n] = sum_k A[m][k]*Bt[n][k] + bias[n], out bf16.
// 128x128 block tile, BK=32, 4 waves each 64x64 (4x4 MFMA 16x16x32).
// N-split support: columns >= nsplit go to out1/bias1 (for fused K/V).
// ---------------------------------------------------------------------------
__global__ __launch_bounds__(256) void gemm_bf16_mfma(
    const bf16* __restrict__ A,     // [M][512]
    const bf16* __restrict__ Bt,    // [N][512]
    const float* __restrict__ bias0, const float* __restrict__ bias1,
    bf16* __restrict__ out0, bf16* __restrict__ out1,
    int nsplit)
{
    const int tid  = threadIdx.x;
    const int wave = tid >> 6, lane = tid & 63;
    const int m0 = blockIdx.x * 128;
    const int n0 = blockIdx.y * 128;
    const int lrow = lane & 15, quad = lane >> 4;
    const int wm = (wave >> 1) * 64, wn = (wave & 1) * 64;

    __shared__ bf16 As[128 * 40];
    __shared__ bf16 Bs[128 * 40];

    f32x4 acc[4][4];
    #pragma unroll
    for (int i = 0; i < 4; ++i)
        #pragma unroll
        for (int j = 0; j < 4; ++j)
            acc[i][j] = (f32x4){0.f, 0.f, 0.f, 0.f};

    for (int k0 = 0; k0 < 512; k0 += 32) {
        #pragma unroll
        for (int i = 0; i < 2; ++i) {
            const int c = tid + i * 256;
            const int r = c >> 2, off = (c & 3) << 3;
            *(bf16x8*)&As[r * 40 + off] = *(const bf16x8*)(A  + (size_t)(m0 + r) * 512 + k0 + off);
            *(bf16x8*)&Bs[r * 40 + off] = *(const bf16x8*)(Bt + (size_t)(n0 + r) * 512 + k0 + off);
        }
        __syncthreads();
        bf16x8 af[4], bfr[4];
        #pragma unroll
        for (int i = 0; i < 4; ++i)
            af[i] = *(const bf16x8*)&As[(wm + i * 16 + lrow) * 40 + quad * 8];
        #pragma unroll
        for (int j = 0; j < 4; ++j)
            bfr[j] = *(const bf16x8*)&Bs[(wn + j * 16 + lrow) * 40 + quad * 8];
        #pragma unroll
        for (int i = 0; i < 4; ++i)
            #pragma unroll
            for (int j = 0; j < 4; ++j)
                acc[i][j] = __builtin_amdgcn_mfma_f32_16x16x32_bf16(af[i], bfr[j], acc[i][j], 0, 0, 0);
        __syncthreads();
    }

    const bool hi = (n0 >= nsplit);
    bf16* outp = hi ? out1 : out0;
    const float* bp = hi ? bias1 : bias0;
    const int nb = hi ? (n0 - nsplit) : n0;
    #pragma unroll
    for (int j = 0; j < 4; ++j) {
        const int gn = nb + wn + j * 16 + lrow;
        const float bv = bp[gn];
        #pragma unroll
        for (int i = 0; i < 4; ++i) {
            const int gm = m0 + wm + i * 16 + quad * 4;
            #pragma unroll
            for (int r = 0; r < 4; ++r)
                outp[(size_t)(gm + r) * 512 + gn] = (bf16)(acc[i][j][r] + bv);
        }
    }
}

// ---------------------------------------------------------------------------
// Attention: 4 threads per q-row (16 dims each), online softmax with
// per-tile rescale against a running reference (exact; ref cancels at end).
// Block: 256 thr = 64 rows x 4 groups, per (b, head). K/V tiles in LDS f32.
// ---------------------------------------------------------------------------
__global__ __launch_bounds__(256) void attn_kernel(
    const bf16* __restrict__ q, const bf16* __restrict__ k,
    const bf16* __restrict__ v, bf16* __restrict__ o)
{
    const int bh = blockIdx.x;
    const int b = bh >> 3, h = bh & 7;
    const int s0 = blockIdx.y * 64;
    const int tid = threadIdx.x;
    const int row = tid >> 2, g = tid & 3;

    __shared__ float Ks[64][68];
    __shared__ float Vs[64][68];

    float qr[16];
    {
        const bf16* qp = q + ((size_t)b * HW + s0 + row) * 512 + h * 64 + g * 16;
        bf16x8 q0 = *(const bf16x8*)qp;
        bf16x8 q1 = *(const bf16x8*)(qp + 8);
        #pragma unroll
        for (int j = 0; j < 8; ++j) { qr[j] = (float)q0[j]; qr[8 + j] = (float)q1[j]; }
    }

    float m_i = 0.0f, l_i = 0.0f;
    float acc[16];
    #pragma unroll
    for (int j = 0; j < 16; ++j) acc[j] = 0.f;

    const bf16* kb = k + (size_t)b * K_LEN * 512 + h * 64;
    const bf16* vb = v + (size_t)b * K_LEN * 512 + h * 64;

    for (int kt = 0; kt < 4; ++kt) {
        __syncthreads();
        {
            const int sr = tid >> 2, sseg = (tid & 3) << 4;
            const bf16* kp = kb + (size_t)(kt * 64 + sr) * 512 + sseg;
            const bf16* vp = vb + (size_t)(kt * 64 + sr) * 512 + sseg;
            bf16x8 k0 = *(const bf16x8*)kp, k1 = *(const bf16x8*)(kp + 8);
            bf16x8 v0 = *(const bf16x8*)vp, v1 = *(const bf16x8*)(vp + 8);
            #pragma unroll
            for (int j = 0; j < 8; ++j) {
                Ks[sr][sseg + j]     = (float)k0[j];
                Ks[sr][sseg + 8 + j] = (float)k1[j];
                Vs[sr][sseg + j]     = (float)v0[j];
                Vs[sr][sseg + 8 + j] = (float)v1[j];
            }
        }
        __syncthreads();

        float tmax = -1e30f;
        for (int kk = 0; kk < 64; ++kk) {
            const f32x4* kr = (const f32x4*)&Ks[kk][g * 16];
            float s = 0.f;
            #pragma unroll
            for (int i = 0; i < 4; ++i) {
                f32x4 t = kr[i];
                s += qr[4*i]*t[0] + qr[4*i+1]*t[1] + qr[4*i+2]*t[2] + qr[4*i+3]*t[3];
            }
            s += __shfl_xor(s, 1, 64);
            s += __shfl_xor(s, 2, 64);
            s *= 0.125f;
            tmax = fmaxf(tmax, s);
            const float w = __expf(s - m_i);
            l_i += w;
            const f32x4* vr = (const f32x4*)&Vs[kk][g * 16];
            #pragma unroll
            for (int i = 0; i < 4; ++i) {
                f32x4 t = vr[i];
                acc[4*i]   += w * t[0];
                acc[4*i+1] += w * t[1];
                acc[4*i+2] += w * t[2];
                acc[4*i+3] += w * t[3];
            }
        }
        // tile-end rescale to new reference
        const float mnew = fmaxf(m_i, tmax);
        const float c = __expf(m_i - mnew);
        l_i *= c;
        #pragma unroll
        for (int j = 0; j < 16; ++j) acc[j] *= c;
        m_i = mnew;
    }

    const float inv = 1.0f / l_i;
    bf16x8 o0, o1;
    #pragma unroll
    for (int j = 0; j < 8; ++j) {
        o0[j] = (bf16)(acc[j] * inv);
        o1[j] = (bf16)(acc[8 + j] * inv);
    }
    bf16* op = o + ((size_t)b * HW + s0 + row) * 512 + h * 64 + g * 16;
    *(bf16x8*)op = o0;
    *(bf16x8*)(op + 8) = o1;
}

// ---------------------------------------------------------------------------
// Residual + LayerNorm + transpose, coalesced both sides via LDS tiles.
// Block: one b, 64 s-rows. Phase 1: stats (wave per row). Phase 2: per
// 64-channel chunk, normalize into LDS then write transposed float4s.
// ---------------------------------------------------------------------------
__global__ __launch_bounds__(256) void ln_kernel(
    const bf16* __restrict__ proj,   // [B*1024][512]
    const bf16* __restrict__ imgb,   // [B*1024][512]
    const float* __restrict__ gamma, const float* __restrict__ beta,
    float* __restrict__ out)         // [B][512][1024]
{
    const int b  = blockIdx.y;
    const int s0 = blockIdx.x * 64;
    const int tid = threadIdx.x;
    const int wave = tid >> 6, lane = tid & 63;

    __shared__ float smu[64], srs[64];
    __shared__ float Y[64][68];

    // Phase 1: per-row mean/var
    for (int rr = 0; rr < 16; ++rr) {
        const int r = wave * 16 + rr;
        const bf16* pp = proj + ((size_t)b * HW + s0 + r) * 512 + lane * 8;
        const bf16* ip = imgb + ((size_t)b * HW + s0 + r) * 512 + lane * 8;
        bf16x8 p8 = *(const bf16x8*)pp;
        bf16x8 i8 = *(const bf16x8*)ip;
        float sum = 0.f, ss = 0.f;
        #pragma unroll
        for (int j = 0; j < 8; ++j) {
            const float y = (float)p8[j] + (float)i8[j];
            sum += y; ss += y * y;
        }
        #pragma unroll
        for (int off = 32; off > 0; off >>= 1) {
            sum += __shfl_xor(sum, off, 64);
            ss  += __shfl_xor(ss, off, 64);
        }
        if (lane == 0) {
            const float mu = sum * (1.f / 512.f);
            const float var = ss * (1.f / 512.f) - mu * mu;
            smu[r] = mu;
            srs[r] = rsqrtf(var + EPS);
        }
    }
    __syncthreads();

    // Phase 2: normalize + transpose-write per 64-channel chunk
    for (int ct = 0; ct < 8; ++ct) {
        const int c0 = ct * 64;
        {
            const int r = tid >> 2, cs = (tid & 3) << 4;
            const bf16* pp = proj + ((size_t)b * HW + s0 + r) * 512 + c0 + cs;
            const bf16* ip = imgb + ((size_t)b * HW + s0 + r) * 512 + c0 + cs;
            bf16x8 p0 = *(const bf16x8*)pp, p1 = *(const bf16x8*)(pp + 8);
            bf16x8 i0 = *(const bf16x8*)ip, i1 = *(const bf16x8*)(ip + 8);
            const float mu = smu[r], rs = srs[r];
            #pragma unroll
            for (int j = 0; j < 8; ++j) {
                const int c = c0 + cs + j;
                Y[r][cs + j]     = ((float)p0[j] + (float)i0[j] - mu) * rs * gamma[c]     + beta[c];
                Y[r][cs + 8 + j] = ((float)p1[j] + (float)i1[j] - mu) * rs * gamma[c + 8] + beta[c + 8];
            }
        }
        __syncthreads();
        {
            const int cc = tid >> 2, so = (tid & 3) << 4;
            float* op = out + ((size_t)b * CCH + c0 + cc) * HW + s0 + so;
            #pragma unroll
            for (int i = 0; i < 4; ++i) {
                float4 o4;
                o4.x = Y[so + i*4 + 0][cc];
                o4.y = Y[so + i*4 + 1][cc];
                o4.z = Y[so + i*4 + 2][cc];
                o4.w = Y[so + i*4 + 3][cc];
                *(float4*)(op + i * 4) = o4;
            }
        }
        __syncthreads();
    }
}

// ---------------------------------------------------------------------------
extern "C" void kernel_launch(void* const* d_in, const int* in_sizes, int n_in,
                              void* d_out, int out_size, void* d_ws, size_t ws_size,
                              hipStream_t stream) {
    const float* img   = (const float*)d_in[0];
    const float* audio = (const float*)d_in[1];
    const float* Wq    = (const float*)d_in[2];
    const float* bq    = (const float*)d_in[3];
    const float* Wk    = (const float*)d_in[4];
    const float* bk    = (const float*)d_in[5];
    const float* Wv    = (const float*)d_in[6];
    const float* bv    = (const float*)d_in[7];
    const float* Wo    = (const float*)d_in[8];
    const float* bo    = (const float*)d_in[9];
    const float* gamma = (const float*)d_in[10];
    const float* beta  = (const float*)d_in[11];

    bf16* wsb    = (bf16*)d_ws;
    bf16* img_bf = wsb;                     // 16*1024*512 = 8388608
    bf16* aud_bf = img_bf + 8388608;        // 16*256*512  = 2097152
    bf16* wT     = aud_bf + 2097152;        // 4*512*512   = 1048576 (q,k,v,o)
    bf16* q_bf   = wT + 1048576;            // 8388608  (proj aliases this)
    bf16* k_bf   = q_bf + 8388608;          // 2097152
    bf16* v_bf   = k_bf + 2097152;          // 2097152
    bf16* a_bf   = v_bf + 2097152;          // 8388608
    bf16* p_bf   = q_bf;                    // alias: q dead after attention

    transpose_cast_img<<<dim3(16, 8, 16), 256, 0, stream>>>(img, img_bf);
    cast_audio<<<dim3(1024), 256, 0, stream>>>(audio, aud_bf);
    transpose_cast_w<<<dim3(8, 8, 4), 256, 0, stream>>>(Wq, Wk, Wv, Wo, wT);

    // Q = img_bf @ Wq^T' : M=16384, N=512
    gemm_bf16_mfma<<<dim3(128, 4), 256, 0, stream>>>(img_bf, wT, bq, bq, q_bf, q_bf, 512);
    // K|V fused: M=4096, N=1024 (cols >=512 -> V)
    gemm_bf16_mfma<<<dim3(32, 8), 256, 0, stream>>>(aud_bf, wT + 1048576 / 2 * 0 + 262144, bk, bv, k_bf, v_bf, 512);
    // Attention
    attn_kernel<<<dim3(128, 16), 256, 0, stream>>>(q_bf, k_bf, v_bf, a_bf);
    // Output projection: M=16384, N=512
    gemm_bf16_mfma<<<dim3(128, 4), 256, 0, stream>>>(a_bf, wT + 3 * 262144, bo, bo, p_bf, p_bf, 512);
    // Residual + LN + transpose
    ln_kernel<<<dim3(16, 16), 256, 0, stream>>>(p_bf, img_bf, gamma, beta, (float*)d_out);
}

// Round 3
// 216.005 us; speedup vs baseline: 3.5832x; 1.8498x over previous
//
#include <hip/hip_runtime.h>
#include <cstddef>

#define B_SZ 16
#define HW 1024
#define CCH 512
#define K_LEN 256
#define N_HEADS 8
#define EPS 1e-5f

typedef __bf16 bf16;
typedef bf16 bf16x8 __attribute__((ext_vector_type(8)));
typedef bf16 bf16x4 __attribute__((ext_vector_type(4)));
typedef float f32x4 __attribute__((ext_vector_type(4)));

// ---------------------------------------------------------------------------
// Transpose+cast img: [B][512][1024] f32 -> [B][1024][512] bf16
// ---------------------------------------------------------------------------
__global__ __launch_bounds__(256) void transpose_cast_img(
    const float* __restrict__ src, bf16* __restrict__ dst)
{
    const int b  = blockIdx.z;
    const int s0 = blockIdx.x * 64;   // src col
    const int c0 = blockIdx.y * 64;   // src row
    __shared__ bf16 T[64][72];
    const int tid = threadIdx.x;
    {
        const int r = tid >> 2, cs = (tid & 3) << 4;
        const float* sp = src + ((size_t)b * CCH + c0 + r) * HW + s0 + cs;
        #pragma unroll
        for (int i = 0; i < 4; ++i) {
            float4 f = *(const float4*)(sp + i * 4);
            T[r][cs + i*4 + 0] = (bf16)f.x;
            T[r][cs + i*4 + 1] = (bf16)f.y;
            T[r][cs + i*4 + 2] = (bf16)f.z;
            T[r][cs + i*4 + 3] = (bf16)f.w;
        }
    }
    __syncthreads();
    {
        const int ss = tid >> 2, ks = (tid & 3) << 4;
        bf16x8 a, b8;
        #pragma unroll
        for (int j = 0; j < 8; ++j) { a[j] = T[ks + j][ss]; b8[j] = T[ks + 8 + j][ss]; }
        bf16* dp = dst + ((size_t)b * HW + s0 + ss) * CCH + c0 + ks;
        *(bf16x8*)dp = a;
        *(bf16x8*)(dp + 8) = b8;
    }
}

// ---------------------------------------------------------------------------
// Transpose+cast the 4 weight matrices: W[k][n] f32 -> Wt[n][k] bf16, packed
// dst layout: [4][512][512] in order q,k,v,o
// ---------------------------------------------------------------------------
__global__ __launch_bounds__(256) void transpose_cast_w(
    const float* __restrict__ Wq, const float* __restrict__ Wk,
    const float* __restrict__ Wv, const float* __restrict__ Wo,
    bf16* __restrict__ dst)
{
    const int w = blockIdx.z;
    const float* src = (w == 0) ? Wq : (w == 1) ? Wk : (w == 2) ? Wv : Wo;
    const int n0 = blockIdx.x * 64;
    const int k0 = blockIdx.y * 64;
    __shared__ bf16 T[64][72];
    const int tid = threadIdx.x;
    {
        const int r = tid >> 2, cs = (tid & 3) << 4;
        const float* sp = src + (size_t)(k0 + r) * CCH + n0 + cs;
        #pragma unroll
        for (int i = 0; i < 4; ++i) {
            float4 f = *(const float4*)(sp + i * 4);
            T[r][cs + i*4 + 0] = (bf16)f.x;
            T[r][cs + i*4 + 1] = (bf16)f.y;
            T[r][cs + i*4 + 2] = (bf16)f.z;
            T[r][cs + i*4 + 3] = (bf16)f.w;
        }
    }
    __syncthreads();
    {
        const int nn = tid >> 2, ks = (tid & 3) << 4;
        bf16x8 a, b8;
        #pragma unroll
        for (int j = 0; j < 8; ++j) { a[j] = T[ks + j][nn]; b8[j] = T[ks + 8 + j][nn]; }
        bf16* dp = dst + (size_t)w * CCH * CCH + (size_t)(n0 + nn) * CCH + k0 + ks;
        *(bf16x8*)dp = a;
        *(bf16x8*)(dp + 8) = b8;
    }
}

// ---------------------------------------------------------------------------
// Elementwise cast audio f32 -> bf16
// ---------------------------------------------------------------------------
__global__ __launch_bounds__(256) void cast_audio(
    const float* __restrict__ src, bf16* __restrict__ dst)
{
    const size_t i = ((size_t)blockIdx.x * 256 + threadIdx.x) * 8;
    float4 a = *(const float4*)(src + i);
    float4 b = *(const float4*)(src + i + 4);
    bf16x8 o;
    o[0] = (bf16)a.x; o[1] = (bf16)a.y; o[2] = (bf16)a.z; o[3] = (bf16)a.w;
    o[4] = (bf16)b.x; o[5] = (bf16)b.y; o[6] = (bf16)b.z; o[7] = (bf16)b.w;
    *(bf16x8*)(dst + i) = o;
}

// ---------------------------------------------------------------------------
// Plain MFMA bf16 GEMM: out[m][n] = sum_k A[m][k]*Bt[n][k] + bias[n]
// 128x128 tile, BK=32, 4 waves, 4x4 MFMA 16x16x32. Used for Q and O proj.
// ---------------------------------------------------------------------------
__global__ __launch_bounds__(256) void gemm_bf16_mfma(
    const bf16* __restrict__ A, const bf16* __restrict__ Bt,
    const float* __restrict__ bias, bf16* __restrict__ out)
{
    const int tid  = threadIdx.x;
    const int wave = tid >> 6, lane = tid & 63;
    const int m0 = blockIdx.x * 128;
    const int n0 = blockIdx.y * 128;
    const int lrow = lane & 15, quad = lane >> 4;
    const int wm = (wave >> 1) * 64, wn = (wave & 1) * 64;

    __shared__ bf16 As[128 * 40];
    __shared__ bf16 Bs[128 * 40];

    f32x4 acc[4][4];
    #pragma unroll
    for (int i = 0; i < 4; ++i)
        #pragma unroll
        for (int j = 0; j < 4; ++j)
            acc[i][j] = (f32x4){0.f, 0.f, 0.f, 0.f};

    for (int k0 = 0; k0 < 512; k0 += 32) {
        #pragma unroll
        for (int i = 0; i < 2; ++i) {
            const int c = tid + i * 256;
            const int r = c >> 2, off = (c & 3) << 3;
            *(bf16x8*)&As[r * 40 + off] = *(const bf16x8*)(A  + (size_t)(m0 + r) * 512 + k0 + off);
            *(bf16x8*)&Bs[r * 40 + off] = *(const bf16x8*)(Bt + (size_t)(n0 + r) * 512 + k0 + off);
        }
        __syncthreads();
        bf16x8 af[4], bfr[4];
        #pragma unroll
        for (int i = 0; i < 4; ++i)
            af[i] = *(const bf16x8*)&As[(wm + i * 16 + lrow) * 40 + quad * 8];
        #pragma unroll
        for (int j = 0; j < 4; ++j)
            bfr[j] = *(const bf16x8*)&Bs[(wn + j * 16 + lrow) * 40 + quad * 8];
        #pragma unroll
        for (int i = 0; i < 4; ++i)
            #pragma unroll
            for (int j = 0; j < 4; ++j)
                acc[i][j] = __builtin_amdgcn_mfma_f32_16x16x32_bf16(af[i], bfr[j], acc[i][j], 0, 0, 0);
        __syncthreads();
    }

    #pragma unroll
    for (int j = 0; j < 4; ++j) {
        const int gn = n0 + wn + j * 16 + lrow;
        const float bv = bias[gn];
        #pragma unroll
        for (int i = 0; i < 4; ++i) {
            const int gm = m0 + wm + i * 16 + quad * 4;
            #pragma unroll
            for (int r = 0; r < 4; ++r)
                out[(size_t)(gm + r) * 512 + gn] = (bf16)(acc[i][j][r] + bv);
        }
    }
}

// ---------------------------------------------------------------------------
// KV GEMM: same main loop, special epilogue:
//   cols <512  -> K, stored per-head row-major: kh[b][h][key][64]
//   cols >=512 -> V, stored per-head TRANSPOSED: vt[b][h][d][256]
// A: audio_bf [4096][512]; Bt: rows 0..511 = Wk^T, 512..1023 = Wv^T.
// ---------------------------------------------------------------------------
__global__ __launch_bounds__(256) void gemm_kv_mfma(
    const bf16* __restrict__ A, const bf16* __restrict__ Bt,
    const float* __restrict__ bk, const float* __restrict__ bv,
    bf16* __restrict__ khout, bf16* __restrict__ vtout)
{
    const int tid  = threadIdx.x;
    const int wave = tid >> 6, lane = tid & 63;
    const int m0 = blockIdx.x * 128;
    const int n0 = blockIdx.y * 128;
    const int lrow = lane & 15, quad = lane >> 4;
    const int wm = (wave >> 1) * 64, wn = (wave & 1) * 64;

    __shared__ bf16 As[128 * 40];
    __shared__ bf16 Bs[128 * 40];

    f32x4 acc[4][4];
    #pragma unroll
    for (int i = 0; i < 4; ++i)
        #pragma unroll
        for (int j = 0; j < 4; ++j)
            acc[i][j] = (f32x4){0.f, 0.f, 0.f, 0.f};

    for (int k0 = 0; k0 < 512; k0 += 32) {
        #pragma unroll
        for (int i = 0; i < 2; ++i) {
            const int c = tid + i * 256;
            const int r = c >> 2, off = (c & 3) << 3;
            *(bf16x8*)&As[r * 40 + off] = *(const bf16x8*)(A  + (size_t)(m0 + r) * 512 + k0 + off);
            *(bf16x8*)&Bs[r * 40 + off] = *(const bf16x8*)(Bt + (size_t)(n0 + r) * 512 + k0 + off);
        }
        __syncthreads();
        bf16x8 af[4], bfr[4];
        #pragma unroll
        for (int i = 0; i < 4; ++i)
            af[i] = *(const bf16x8*)&As[(wm + i * 16 + lrow) * 40 + quad * 8];
        #pragma unroll
        for (int j = 0; j < 4; ++j)
            bfr[j] = *(const bf16x8*)&Bs[(wn + j * 16 + lrow) * 40 + quad * 8];
        #pragma unroll
        for (int i = 0; i < 4; ++i)
            #pragma unroll
            for (int j = 0; j < 4; ++j)
                acc[i][j] = __builtin_amdgcn_mfma_f32_16x16x32_bf16(af[i], bfr[j], acc[i][j], 0, 0, 0);
        __syncthreads();
    }

    #pragma unroll
    for (int j = 0; j < 4; ++j) {
        const int gn = n0 + wn + j * 16 + lrow;
        if (gn < 512) {
            const int h = gn >> 6, d = gn & 63;
            const float bias = bk[gn];
            #pragma unroll
            for (int i = 0; i < 4; ++i) {
                const int gm = m0 + wm + i * 16 + quad * 4;
                const int b = gm >> 8, key = gm & 255;
                bf16* base = khout + ((((size_t)b * N_HEADS + h) * K_LEN) + key) * 64 + d;
                #pragma unroll
                for (int r = 0; r < 4; ++r)
                    base[(size_t)r * 64] = (bf16)(acc[i][j][r] + bias);
            }
        } else {
            const int ch = gn - 512;
            const int h = ch >> 6, d = ch & 63;
            const float bias = bv[ch];
            #pragma unroll
            for (int i = 0; i < 4; ++i) {
                const int gm = m0 + wm + i * 16 + quad * 4;
                const int b = gm >> 8, key = gm & 255;
                bf16x4 pk;
                #pragma unroll
                for (int r = 0; r < 4; ++r) pk[r] = (bf16)(acc[i][j][r] + bias);
                *(bf16x4*)(vtout + (((size_t)b * N_HEADS + h) * 64 + d) * K_LEN + key) = pk;
            }
        }
    }
}

// ---------------------------------------------------------------------------
// MFMA attention. One block = one (b,h), 64 q-rows; 4 waves x 16 rows.
// Phase 1: S^T = K @ Q^T via mfma (A=K frags, B=Q frags). C-layout:
//   lane: qrow = lane&15, key = mtile*16 + quad*4 + reg  (4 consecutive keys)
// Phase 2: exact softmax (shfl_xor 16/32 across quads), P packed bf16x4 ->
//   LDS Pt[qrow][key] via ds_write_b64 (overlays Ks after barrier).
// Phase 3: out^T = Vt @ Pt via mfma (A=Vt frags, B=Pt frags, ds_read_b128).
//   C-layout: lane: qrow = lane&15, dim = mtile*16 + quad*4 + reg -> 8B stores.
// ---------------------------------------------------------------------------
__global__ __launch_bounds__(256) void attn_mfma(
    const bf16* __restrict__ q,    // [B*1024][512]
    const bf16* __restrict__ kh,   // [B][H][256][64]
    const bf16* __restrict__ vt,   // [B][H][64][256]
    bf16* __restrict__ o)          // [B*1024][512]
{
    const int bh = blockIdx.x;          // b*8+h
    const int s0 = blockIdx.y * 64;
    const int tid = threadIdx.x;
    const int wave = tid >> 6, lane = tid & 63;
    const int l15 = lane & 15, quad = lane >> 4;
    const int b = bh >> 3, h = bh & 7;

    __shared__ bf16 KsPt[18432];   // Ks [256][72]; later Pt: 4 waves x [16][264]
    __shared__ bf16 Vs[16896];     // Vt [64][264]

    const bf16* khb = kh + (size_t)bh * K_LEN * 64;
    const bf16* vtb = vt + (size_t)bh * 64 * K_LEN;

    // Stage K and V^T into LDS (padded strides: 72 / 264 bf16 -> 2-way free)
    #pragma unroll
    for (int i = 0; i < 8; ++i) {
        const int chunk = tid + (i << 8);            // 0..2047 chunks of 8 bf16
        const int key = chunk >> 3, dseg = (chunk & 7) << 3;
        *(bf16x8*)&KsPt[key * 72 + dseg] = *(const bf16x8*)(khb + key * 64 + dseg);
        const int d = chunk >> 5, kseg = (chunk & 31) << 3;
        *(bf16x8*)&Vs[d * 264 + kseg] = *(const bf16x8*)(vtb + d * 256 + kseg);
    }
    __syncthreads();

    // Q fragments (B operand): Q[qrow][dim], k-steps dim 0..31 and 32..63
    const int qrow = s0 + wave * 16 + l15;
    const bf16* qp = q + ((size_t)(b * HW + qrow)) * 512 + h * 64 + quad * 8;
    const bf16x8 qf0 = *(const bf16x8*)qp;
    const bf16x8 qf1 = *(const bf16x8*)(qp + 32);

    // Phase 1: S^T
    f32x4 acc[16];
    #pragma unroll
    for (int m = 0; m < 16; ++m) acc[m] = (f32x4){0.f, 0.f, 0.f, 0.f};
    #pragma unroll
    for (int m = 0; m < 16; ++m) {
        const bf16x8 a0 = *(const bf16x8*)&KsPt[(m * 16 + l15) * 72 + quad * 8];
        const bf16x8 a1 = *(const bf16x8*)&KsPt[(m * 16 + l15) * 72 + 32 + quad * 8];
        acc[m] = __builtin_amdgcn_mfma_f32_16x16x32_bf16(a0, qf0, acc[m], 0, 0, 0);
        acc[m] = __builtin_amdgcn_mfma_f32_16x16x32_bf16(a1, qf1, acc[m], 0, 0, 0);
    }

    // Phase 2: exact softmax over 256 keys for qrow = lane&15
    float mx = -1e30f;
    #pragma unroll
    for (int m = 0; m < 16; ++m) {
        mx = fmaxf(mx, fmaxf(fmaxf(acc[m][0], acc[m][1]), fmaxf(acc[m][2], acc[m][3])));
    }
    mx = fmaxf(mx, __shfl_xor(mx, 16, 64));
    mx = fmaxf(mx, __shfl_xor(mx, 32, 64));

    __syncthreads();   // all waves done reading Ks; safe to overlay Pt

    bf16* PtW = &KsPt[wave * 4224];   // [16][264]
    float l_sum = 0.f;
    #pragma unroll
    for (int m = 0; m < 16; ++m) {
        bf16x4 pk;
        #pragma unroll
        for (int r = 0; r < 4; ++r) {
            const float p = __expf((acc[m][r] - mx) * 0.125f);
            l_sum += p;
            pk[r] = (bf16)p;
        }
        *(bf16x4*)&PtW[l15 * 264 + m * 16 + quad * 4] = pk;
    }
    l_sum += __shfl_xor(l_sum, 16, 64);
    l_sum += __shfl_xor(l_sum, 32, 64);
    __syncthreads();   // Pt writes visible

    // Phase 3: out^T = Vt @ Pt
    f32x4 oacc[4];
    #pragma unroll
    for (int m = 0; m < 4; ++m) oacc[m] = (f32x4){0.f, 0.f, 0.f, 0.f};
    #pragma unroll
    for (int s = 0; s < 8; ++s) {
        const bf16x8 pb = *(const bf16x8*)&PtW[l15 * 264 + s * 32 + quad * 8];
        #pragma unroll
        for (int m = 0; m < 4; ++m) {
            const bf16x8 va = *(const bf16x8*)&Vs[(m * 16 + l15) * 264 + s * 32 + quad * 8];
            oacc[m] = __builtin_amdgcn_mfma_f32_16x16x32_bf16(va, pb, oacc[m], 0, 0, 0);
        }
    }

    const float inv = 1.0f / l_sum;
    bf16* op = o + ((size_t)(b * HW + qrow)) * 512 + h * 64 + quad * 4;
    #pragma unroll
    for (int m = 0; m < 4; ++m) {
        bf16x4 ov;
        #pragma unroll
        for (int r = 0; r < 4; ++r) ov[r] = (bf16)(oacc[m][r] * inv);
        *(bf16x4*)&op[m * 16] = ov;
    }
}

// ---------------------------------------------------------------------------
// Residual + LayerNorm + transpose (unchanged from R2)
// ---------------------------------------------------------------------------
__global__ __launch_bounds__(256) void ln_kernel(
    const bf16* __restrict__ proj, const bf16* __restrict__ imgb,
    const float* __restrict__ gamma, const float* __restrict__ beta,
    float* __restrict__ out)
{
    const int b  = blockIdx.y;
    const int s0 = blockIdx.x * 64;
    const int tid = threadIdx.x;
    const int wave = tid >> 6, lane = tid & 63;

    __shared__ float smu[64], srs[64];
    __shared__ float Y[64][68];

    for (int rr = 0; rr < 16; ++rr) {
        const int r = wave * 16 + rr;
        const bf16* pp = proj + ((size_t)b * HW + s0 + r) * 512 + lane * 8;
        const bf16* ip = imgb + ((size_t)b * HW + s0 + r) * 512 + lane * 8;
        bf16x8 p8 = *(const bf16x8*)pp;
        bf16x8 i8 = *(const bf16x8*)ip;
        float sum = 0.f, ss = 0.f;
        #pragma unroll
        for (int j = 0; j < 8; ++j) {
            const float y = (float)p8[j] + (float)i8[j];
            sum += y; ss += y * y;
        }
        #pragma unroll
        for (int off = 32; off > 0; off >>= 1) {
            sum += __shfl_xor(sum, off, 64);
            ss  += __shfl_xor(ss, off, 64);
        }
        if (lane == 0) {
            const float mu = sum * (1.f / 512.f);
            const float var = ss * (1.f / 512.f) - mu * mu;
            smu[r] = mu;
            srs[r] = rsqrtf(var + EPS);
        }
    }
    __syncthreads();

    for (int ct = 0; ct < 8; ++ct) {
        const int c0 = ct * 64;
        {
            const int r = tid >> 2, cs = (tid & 3) << 4;
            const bf16* pp = proj + ((size_t)b * HW + s0 + r) * 512 + c0 + cs;
            const bf16* ip = imgb + ((size_t)b * HW + s0 + r) * 512 + c0 + cs;
            bf16x8 p0 = *(const bf16x8*)pp, p1 = *(const bf16x8*)(pp + 8);
            bf16x8 i0 = *(const bf16x8*)ip, i1 = *(const bf16x8*)(ip + 8);
            const float mu = smu[r], rs = srs[r];
            #pragma unroll
            for (int j = 0; j < 8; ++j) {
                const int c = c0 + cs + j;
                Y[r][cs + j]     = ((float)p0[j] + (float)i0[j] - mu) * rs * gamma[c]     + beta[c];
                Y[r][cs + 8 + j] = ((float)p1[j] + (float)i1[j] - mu) * rs * gamma[c + 8] + beta[c + 8];
            }
        }
        __syncthreads();
        {
            const int cc = tid >> 2, so = (tid & 3) << 4;
            float* op = out + ((size_t)b * CCH + c0 + cc) * HW + s0 + so;
            #pragma unroll
            for (int i = 0; i < 4; ++i) {
                float4 o4;
                o4.x = Y[so + i*4 + 0][cc];
                o4.y = Y[so + i*4 + 1][cc];
                o4.z = Y[so + i*4 + 2][cc];
                o4.w = Y[so + i*4 + 3][cc];
                *(float4*)(op + i * 4) = o4;
            }
        }
        __syncthreads();
    }
}

// ---------------------------------------------------------------------------
extern "C" void kernel_launch(void* const* d_in, const int* in_sizes, int n_in,
                              void* d_out, int out_size, void* d_ws, size_t ws_size,
                              hipStream_t stream) {
    const float* img   = (const float*)d_in[0];
    const float* audio = (const float*)d_in[1];
    const float* Wq    = (const float*)d_in[2];
    const float* bq    = (const float*)d_in[3];
    const float* Wk    = (const float*)d_in[4];
    const float* bk    = (const float*)d_in[5];
    const float* Wv    = (const float*)d_in[6];
    const float* bv    = (const float*)d_in[7];
    const float* Wo    = (const float*)d_in[8];
    const float* bo    = (const float*)d_in[9];
    const float* gamma = (const float*)d_in[10];
    const float* beta  = (const float*)d_in[11];

    bf16* wsb    = (bf16*)d_ws;
    bf16* img_bf = wsb;                     // 8388608
    bf16* aud_bf = img_bf + 8388608;        // 2097152
    bf16* wT     = aud_bf + 2097152;        // 4*262144 (q,k,v,o)
    bf16* q_bf   = wT + 1048576;            // 8388608
    bf16* kh_bf  = q_bf + 8388608;          // 2097152  [B][H][256][64]
    bf16* vt_bf  = kh_bf + 2097152;         // 2097152  [B][H][64][256]
    bf16* a_bf   = vt_bf + 2097152;         // 8388608
    bf16* p_bf   = q_bf;                    // alias: q dead after attention

    transpose_cast_img<<<dim3(16, 8, 16), 256, 0, stream>>>(img, img_bf);
    cast_audio<<<dim3(1024), 256, 0, stream>>>(audio, aud_bf);
    transpose_cast_w<<<dim3(8, 8, 4), 256, 0, stream>>>(Wq, Wk, Wv, Wo, wT);

    // Q projection: M=16384, N=512
    gemm_bf16_mfma<<<dim3(128, 4), 256, 0, stream>>>(img_bf, wT, bq, q_bf);
    // K|V fused: M=4096, N=1024 (Bt rows 0..511 = Wk^T, 512..1023 = Wv^T)
    gemm_kv_mfma<<<dim3(32, 8), 256, 0, stream>>>(aud_bf, wT + 262144, bk, bv, kh_bf, vt_bf);
    // MFMA attention
    attn_mfma<<<dim3(B_SZ * N_HEADS, HW / 64), 256, 0, stream>>>(q_bf, kh_bf, vt_bf, a_bf);
    // Output projection: M=16384, N=512
    gemm_bf16_mfma<<<dim3(128, 4), 256, 0, stream>>>(a_bf, wT + 3 * 262144, bo, p_bf);
    // Residual + LN + transpose
    ln_kernel<<<dim3(16, 16), 256, 0, stream>>>(p_bf, img_bf, gamma, beta, (float*)d_out);
}

// Round 4
// 198.080 us; speedup vs baseline: 3.9075x; 1.0905x over previous
//
#include <hip/hip_runtime.h>
#include <cstddef>

#define B_SZ 16
#define HW 1024
#define CCH 512
#define K_LEN 256
#define N_HEADS 8
#define EPS 1e-5f

typedef __bf16 bf16;
typedef bf16 bf16x8 __attribute__((ext_vector_type(8)));
typedef bf16 bf16x4 __attribute__((ext_vector_type(4)));
typedef float f32x4 __attribute__((ext_vector_type(4)));

// async global->LDS, 16B per lane; LDS dest is wave-uniform base + lane*16
__device__ __forceinline__ void gl_lds16(const bf16* g, bf16* l) {
    __builtin_amdgcn_global_load_lds(
        (const __attribute__((address_space(1))) void*)g,
        (__attribute__((address_space(3))) void*)l, 16, 0, 0);
}

// ---------------------------------------------------------------------------
// Transpose+cast img: [B][512][1024] f32 -> [B][1024][512] bf16
// ---------------------------------------------------------------------------
__global__ __launch_bounds__(256) void transpose_cast_img(
    const float* __restrict__ src, bf16* __restrict__ dst)
{
    const int b  = blockIdx.z;
    const int s0 = blockIdx.x * 64;
    const int c0 = blockIdx.y * 64;
    __shared__ bf16 T[64][72];
    const int tid = threadIdx.x;
    {
        const int r = tid >> 2, cs = (tid & 3) << 4;
        const float* sp = src + ((size_t)b * CCH + c0 + r) * HW + s0 + cs;
        #pragma unroll
        for (int i = 0; i < 4; ++i) {
            float4 f = *(const float4*)(sp + i * 4);
            T[r][cs + i*4 + 0] = (bf16)f.x;
            T[r][cs + i*4 + 1] = (bf16)f.y;
            T[r][cs + i*4 + 2] = (bf16)f.z;
            T[r][cs + i*4 + 3] = (bf16)f.w;
        }
    }
    __syncthreads();
    {
        const int ss = tid >> 2, ks = (tid & 3) << 4;
        bf16x8 a, b8;
        #pragma unroll
        for (int j = 0; j < 8; ++j) { a[j] = T[ks + j][ss]; b8[j] = T[ks + 8 + j][ss]; }
        bf16* dp = dst + ((size_t)b * HW + s0 + ss) * CCH + c0 + ks;
        *(bf16x8*)dp = a;
        *(bf16x8*)(dp + 8) = b8;
    }
}

// ---------------------------------------------------------------------------
// Transpose+cast weights: W[k][n] f32 -> Wt[n][k] bf16, packed [4][512][512]
// ---------------------------------------------------------------------------
__global__ __launch_bounds__(256) void transpose_cast_w(
    const float* __restrict__ Wq, const float* __restrict__ Wk,
    const float* __restrict__ Wv, const float* __restrict__ Wo,
    bf16* __restrict__ dst)
{
    const int w = blockIdx.z;
    const float* src = (w == 0) ? Wq : (w == 1) ? Wk : (w == 2) ? Wv : Wo;
    const int n0 = blockIdx.x * 64;
    const int k0 = blockIdx.y * 64;
    __shared__ bf16 T[64][72];
    const int tid = threadIdx.x;
    {
        const int r = tid >> 2, cs = (tid & 3) << 4;
        const float* sp = src + (size_t)(k0 + r) * CCH + n0 + cs;
        #pragma unroll
        for (int i = 0; i < 4; ++i) {
            float4 f = *(const float4*)(sp + i * 4);
            T[r][cs + i*4 + 0] = (bf16)f.x;
            T[r][cs + i*4 + 1] = (bf16)f.y;
            T[r][cs + i*4 + 2] = (bf16)f.z;
            T[r][cs + i*4 + 3] = (bf16)f.w;
        }
    }
    __syncthreads();
    {
        const int nn = tid >> 2, ks = (tid & 3) << 4;
        bf16x8 a, b8;
        #pragma unroll
        for (int j = 0; j < 8; ++j) { a[j] = T[ks + j][nn]; b8[j] = T[ks + 8 + j][nn]; }
        bf16* dp = dst + (size_t)w * CCH * CCH + (size_t)(n0 + nn) * CCH + k0 + ks;
        *(bf16x8*)dp = a;
        *(bf16x8*)(dp + 8) = b8;
    }
}

// ---------------------------------------------------------------------------
// Elementwise cast audio f32 -> bf16
// ---------------------------------------------------------------------------
__global__ __launch_bounds__(256) void cast_audio(
    const float* __restrict__ src, bf16* __restrict__ dst)
{
    const size_t i = ((size_t)blockIdx.x * 256 + threadIdx.x) * 8;
    float4 a = *(const float4*)(src + i);
    float4 b = *(const float4*)(src + i + 4);
    bf16x8 o;
    o[0] = (bf16)a.x; o[1] = (bf16)a.y; o[2] = (bf16)a.z; o[3] = (bf16)a.w;
    o[4] = (bf16)b.x; o[5] = (bf16)b.y; o[6] = (bf16)b.z; o[7] = (bf16)b.w;
    *(bf16x8*)(dst + i) = o;
}

// ---------------------------------------------------------------------------
// MFMA bf16 GEMM (m97-style): out[m][n] = sum_k A[m][k]*Bt[n][k] + bias[n]
// 128x128 tile, BK=32, global_load_lds width-16 staging, unpadded [128][32].
// MFMA operands swapped (Ct layout): lane&15 = m, quad*4+reg = n ->
// each lane stores 4 consecutive n as one 8B bf16x4.
// ---------------------------------------------------------------------------
__global__ __launch_bounds__(256) void gemm_bf16_mfma(
    const bf16* __restrict__ A, const bf16* __restrict__ Bt,
    const float* __restrict__ bias, bf16* __restrict__ out)
{
    const int tid  = threadIdx.x;
    const int wave = tid >> 6, lane = tid & 63;
    const int m0 = blockIdx.x * 128;
    const int n0 = blockIdx.y * 128;
    const int l15 = lane & 15, quad = lane >> 4;
    const int wm = (wave >> 1) * 64, wn = (wave & 1) * 64;

    __shared__ bf16 As[128 * 32];
    __shared__ bf16 Bs[128 * 32];

    const int r16 = lane >> 2;          // row within 16-row chunk
    const int ks  = (lane & 3) * 8;     // k-seg (8 elems = 16B)

    f32x4 acc[4][4];
    #pragma unroll
    for (int i = 0; i < 4; ++i)
        #pragma unroll
        for (int j = 0; j < 4; ++j)
            acc[i][j] = (f32x4){0.f, 0.f, 0.f, 0.f};

    for (int k0 = 0; k0 < 512; k0 += 32) {
        #pragma unroll
        for (int i = 0; i < 2; ++i) {
            const int c = wave * 2 + i;           // chunk 0..7 (16 rows each)
            gl_lds16(A  + (size_t)(m0 + c * 16 + r16) * 512 + k0 + ks, &As[c * 512]);
            gl_lds16(Bt + (size_t)(n0 + c * 16 + r16) * 512 + k0 + ks, &Bs[c * 512]);
        }
        __syncthreads();
        bf16x8 af[4], bfr[4];
        #pragma unroll
        for (int i = 0; i < 4; ++i)
            af[i] = *(const bf16x8*)&As[(wm + i * 16 + l15) * 32 + quad * 8];
        #pragma unroll
        for (int j = 0; j < 4; ++j)
            bfr[j] = *(const bf16x8*)&Bs[(wn + j * 16 + l15) * 32 + quad * 8];
        #pragma unroll
        for (int i = 0; i < 4; ++i)
            #pragma unroll
            for (int j = 0; j < 4; ++j)
                acc[i][j] = __builtin_amdgcn_mfma_f32_16x16x32_bf16(bfr[j], af[i], acc[i][j], 0, 0, 0);
        __syncthreads();
    }

    #pragma unroll
    for (int j = 0; j < 4; ++j) {
        const int gn = n0 + wn + j * 16 + quad * 4;
        const float4 bv4 = *(const float4*)(bias + gn);
        const float bb[4] = {bv4.x, bv4.y, bv4.z, bv4.w};
        #pragma unroll
        for (int i = 0; i < 4; ++i) {
            const int gm = m0 + wm + i * 16 + l15;
            bf16x4 ov;
            #pragma unroll
            for (int r = 0; r < 4; ++r) ov[r] = (bf16)(acc[i][j][r] + bb[r]);
            *(bf16x4*)(out + (size_t)gm * 512 + gn) = ov;
        }
    }
}

// ---------------------------------------------------------------------------
// KV GEMM: same staging; original MFMA orientation (lane&15 = n).
//   cols <512  -> K, per-head row-major kh[b][h][key][64]
//   cols >=512 -> V, per-head transposed vt[b][h][d][256] (bf16x4 stores)
// ---------------------------------------------------------------------------
__global__ __launch_bounds__(256) void gemm_kv_mfma(
    const bf16* __restrict__ A, const bf16* __restrict__ Bt,
    const float* __restrict__ bk, const float* __restrict__ bv,
    bf16* __restrict__ khout, bf16* __restrict__ vtout)
{
    const int tid  = threadIdx.x;
    const int wave = tid >> 6, lane = tid & 63;
    const int m0 = blockIdx.x * 128;
    const int n0 = blockIdx.y * 128;
    const int l15 = lane & 15, quad = lane >> 4;
    const int wm = (wave >> 1) * 64, wn = (wave & 1) * 64;

    __shared__ bf16 As[128 * 32];
    __shared__ bf16 Bs[128 * 32];

    const int r16 = lane >> 2;
    const int ks  = (lane & 3) * 8;

    f32x4 acc[4][4];
    #pragma unroll
    for (int i = 0; i < 4; ++i)
        #pragma unroll
        for (int j = 0; j < 4; ++j)
            acc[i][j] = (f32x4){0.f, 0.f, 0.f, 0.f};

    for (int k0 = 0; k0 < 512; k0 += 32) {
        #pragma unroll
        for (int i = 0; i < 2; ++i) {
            const int c = wave * 2 + i;
            gl_lds16(A  + (size_t)(m0 + c * 16 + r16) * 512 + k0 + ks, &As[c * 512]);
            gl_lds16(Bt + (size_t)(n0 + c * 16 + r16) * 512 + k0 + ks, &Bs[c * 512]);
        }
        __syncthreads();
        bf16x8 af[4], bfr[4];
        #pragma unroll
        for (int i = 0; i < 4; ++i)
            af[i] = *(const bf16x8*)&As[(wm + i * 16 + l15) * 32 + quad * 8];
        #pragma unroll
        for (int j = 0; j < 4; ++j)
            bfr[j] = *(const bf16x8*)&Bs[(wn + j * 16 + l15) * 32 + quad * 8];
        #pragma unroll
        for (int i = 0; i < 4; ++i)
            #pragma unroll
            for (int j = 0; j < 4; ++j)
                acc[i][j] = __builtin_amdgcn_mfma_f32_16x16x32_bf16(af[i], bfr[j], acc[i][j], 0, 0, 0);
        __syncthreads();
    }

    #pragma unroll
    for (int j = 0; j < 4; ++j) {
        const int gn = n0 + wn + j * 16 + l15;
        if (gn < 512) {
            const int h = gn >> 6, d = gn & 63;
            const float bias = bk[gn];
            #pragma unroll
            for (int i = 0; i < 4; ++i) {
                const int gm = m0 + wm + i * 16 + quad * 4;
                const int b = gm >> 8, key = gm & 255;
                bf16* base = khout + ((((size_t)b * N_HEADS + h) * K_LEN) + key) * 64 + d;
                #pragma unroll
                for (int r = 0; r < 4; ++r)
                    base[(size_t)r * 64] = (bf16)(acc[i][j][r] + bias);
            }
        } else {
            const int ch = gn - 512;
            const int h = ch >> 6, d = ch & 63;
            const float bias = bv[ch];
            #pragma unroll
            for (int i = 0; i < 4; ++i) {
                const int gm = m0 + wm + i * 16 + quad * 4;
                const int b = gm >> 8, key = gm & 255;
                bf16x4 pk;
                #pragma unroll
                for (int r = 0; r < 4; ++r) pk[r] = (bf16)(acc[i][j][r] + bias);
                *(bf16x4*)(vtout + (((size_t)b * N_HEADS + h) * 64 + d) * K_LEN + key) = pk;
            }
        }
    }
}

// ---------------------------------------------------------------------------
// MFMA attention (unchanged from R3): S^T trick + exact softmax + Vt@Pt.
// ---------------------------------------------------------------------------
__global__ __launch_bounds__(256) void attn_mfma(
    const bf16* __restrict__ q,    // [B*1024][512]
    const bf16* __restrict__ kh,   // [B][H][256][64]
    const bf16* __restrict__ vt,   // [B][H][64][256]
    bf16* __restrict__ o)          // [B*1024][512]
{
    const int bh = blockIdx.x;
    const int s0 = blockIdx.y * 64;
    const int tid = threadIdx.x;
    const int wave = tid >> 6, lane = tid & 63;
    const int l15 = lane & 15, quad = lane >> 4;
    const int b = bh >> 3, h = bh & 7;

    __shared__ bf16 KsPt[18432];   // Ks [256][72]; later Pt: 4 waves x [16][264]
    __shared__ bf16 Vs[16896];     // Vt [64][264]

    const bf16* khb = kh + (size_t)bh * K_LEN * 64;
    const bf16* vtb = vt + (size_t)bh * 64 * K_LEN;

    #pragma unroll
    for (int i = 0; i < 8; ++i) {
        const int chunk = tid + (i << 8);
        const int key = chunk >> 3, dseg = (chunk & 7) << 3;
        *(bf16x8*)&KsPt[key * 72 + dseg] = *(const bf16x8*)(khb + key * 64 + dseg);
        const int d = chunk >> 5, kseg = (chunk & 31) << 3;
        *(bf16x8*)&Vs[d * 264 + kseg] = *(const bf16x8*)(vtb + d * 256 + kseg);
    }
    __syncthreads();

    const int qrow = s0 + wave * 16 + l15;
    const bf16* qp = q + ((size_t)(b * HW + qrow)) * 512 + h * 64 + quad * 8;
    const bf16x8 qf0 = *(const bf16x8*)qp;
    const bf16x8 qf1 = *(const bf16x8*)(qp + 32);

    f32x4 acc[16];
    #pragma unroll
    for (int m = 0; m < 16; ++m) acc[m] = (f32x4){0.f, 0.f, 0.f, 0.f};
    #pragma unroll
    for (int m = 0; m < 16; ++m) {
        const bf16x8 a0 = *(const bf16x8*)&KsPt[(m * 16 + l15) * 72 + quad * 8];
        const bf16x8 a1 = *(const bf16x8*)&KsPt[(m * 16 + l15) * 72 + 32 + quad * 8];
        acc[m] = __builtin_amdgcn_mfma_f32_16x16x32_bf16(a0, qf0, acc[m], 0, 0, 0);
        acc[m] = __builtin_amdgcn_mfma_f32_16x16x32_bf16(a1, qf1, acc[m], 0, 0, 0);
    }

    float mx = -1e30f;
    #pragma unroll
    for (int m = 0; m < 16; ++m)
        mx = fmaxf(mx, fmaxf(fmaxf(acc[m][0], acc[m][1]), fmaxf(acc[m][2], acc[m][3])));
    mx = fmaxf(mx, __shfl_xor(mx, 16, 64));
    mx = fmaxf(mx, __shfl_xor(mx, 32, 64));

    __syncthreads();

    bf16* PtW = &KsPt[wave * 4224];
    float l_sum = 0.f;
    #pragma unroll
    for (int m = 0; m < 16; ++m) {
        bf16x4 pk;
        #pragma unroll
        for (int r = 0; r < 4; ++r) {
            const float p = __expf((acc[m][r] - mx) * 0.125f);
            l_sum += p;
            pk[r] = (bf16)p;
        }
        *(bf16x4*)&PtW[l15 * 264 + m * 16 + quad * 4] = pk;
    }
    l_sum += __shfl_xor(l_sum, 16, 64);
    l_sum += __shfl_xor(l_sum, 32, 64);
    __syncthreads();

    f32x4 oacc[4];
    #pragma unroll
    for (int m = 0; m < 4; ++m) oacc[m] = (f32x4){0.f, 0.f, 0.f, 0.f};
    #pragma unroll
    for (int s = 0; s < 8; ++s) {
        const bf16x8 pb = *(const bf16x8*)&PtW[l15 * 264 + s * 32 + quad * 8];
        #pragma unroll
        for (int m = 0; m < 4; ++m) {
            const bf16x8 va = *(const bf16x8*)&Vs[(m * 16 + l15) * 264 + s * 32 + quad * 8];
            oacc[m] = __builtin_amdgcn_mfma_f32_16x16x32_bf16(va, pb, oacc[m], 0, 0, 0);
        }
    }

    const float inv = 1.0f / l_sum;
    bf16* op = o + ((size_t)(b * HW + qrow)) * 512 + h * 64 + quad * 4;
    #pragma unroll
    for (int m = 0; m < 4; ++m) {
        bf16x4 ov;
        #pragma unroll
        for (int r = 0; r < 4; ++r) ov[r] = (bf16)(oacc[m][r] * inv);
        *(bf16x4*)&op[m * 16] = ov;
    }
}

// ---------------------------------------------------------------------------
// Residual + LayerNorm + transpose, single global read.
// Block: 32 s-rows of one b. Phase 1: wave per 8 rows, y in regs, stats via
// shuffle, write normalized Y to LDS [32][513] (pad -> conflict-free cols).
// Phase 2: transpose-write float4 to out[b][c][s].
// ---------------------------------------------------------------------------
__global__ __launch_bounds__(256) void ln_kernel(
    const bf16* __restrict__ proj, const bf16* __restrict__ imgb,
    const float* __restrict__ gamma, const float* __restrict__ beta,
    float* __restrict__ out)
{
    const int b  = blockIdx.y;
    const int s0 = blockIdx.x * 32;
    const int tid = threadIdx.x;
    const int wave = tid >> 6, lane = tid & 63;

    __shared__ float Y[32][513];

    const int cb = lane * 8;
    const float4 g0 = *(const float4*)(gamma + cb);
    const float4 g1 = *(const float4*)(gamma + cb + 4);
    const float4 b0 = *(const float4*)(beta + cb);
    const float4 b1 = *(const float4*)(beta + cb + 4);
    const float gg[8] = {g0.x, g0.y, g0.z, g0.w, g1.x, g1.y, g1.z, g1.w};
    const float bb[8] = {b0.x, b0.y, b0.z, b0.w, b1.x, b1.y, b1.z, b1.w};

    #pragma unroll
    for (int rr = 0; rr < 8; ++rr) {
        const int ss = wave * 8 + rr;
        const size_t row = (size_t)b * HW + s0 + ss;
        bf16x8 p8 = *(const bf16x8*)(proj + row * 512 + cb);
        bf16x8 i8 = *(const bf16x8*)(imgb + row * 512 + cb);
        float y[8];
        float sum = 0.f, sq = 0.f;
        #pragma unroll
        for (int j = 0; j < 8; ++j) {
            y[j] = (float)p8[j] + (float)i8[j];
            sum += y[j]; sq += y[j] * y[j];
        }
        #pragma unroll
        for (int off = 32; off > 0; off >>= 1) {
            sum += __shfl_xor(sum, off, 64);
            sq  += __shfl_xor(sq, off, 64);
        }
        const float mu = sum * (1.f / 512.f);
        const float rs = rsqrtf(sq * (1.f / 512.f) - mu * mu + EPS);
        #pragma unroll
        for (int j = 0; j < 8; ++j)
            Y[ss][cb + j] = (y[j] - mu) * rs * gg[j] + bb[j];
    }
    __syncthreads();

    #pragma unroll
    for (int it = 0; it < 16; ++it) {
        const int idx = it * 256 + tid;      // 0..4095
        const int c = idx >> 3, sseg = (idx & 7) << 2;
        float4 o4;
        o4.x = Y[sseg + 0][c];
        o4.y = Y[sseg + 1][c];
        o4.z = Y[sseg + 2][c];
        o4.w = Y[sseg + 3][c];
        *(float4*)(out + ((size_t)b * CCH + c) * HW + s0 + sseg) = o4;
    }
}

// ---------------------------------------------------------------------------
extern "C" void kernel_launch(void* const* d_in, const int* in_sizes, int n_in,
                              void* d_out, int out_size, void* d_ws, size_t ws_size,
                              hipStream_t stream) {
    const float* img   = (const float*)d_in[0];
    const float* audio = (const float*)d_in[1];
    const float* Wq    = (const float*)d_in[2];
    const float* bq    = (const float*)d_in[3];
    const float* Wk    = (const float*)d_in[4];
    const float* bk    = (const float*)d_in[5];
    const float* Wv    = (const float*)d_in[6];
    const float* bv    = (const float*)d_in[7];
    const float* Wo    = (const float*)d_in[8];
    const float* bo    = (const float*)d_in[9];
    const float* gamma = (const float*)d_in[10];
    const float* beta  = (const float*)d_in[11];

    bf16* wsb    = (bf16*)d_ws;
    bf16* img_bf = wsb;                     // 8388608
    bf16* aud_bf = img_bf + 8388608;        // 2097152
    bf16* wT     = aud_bf + 2097152;        // 4*262144 (q,k,v,o)
    bf16* q_bf   = wT + 1048576;            // 8388608
    bf16* kh_bf  = q_bf + 8388608;          // 2097152  [B][H][256][64]
    bf16* vt_bf  = kh_bf + 2097152;         // 2097152  [B][H][64][256]
    bf16* a_bf   = vt_bf + 2097152;         // 8388608
    bf16* p_bf   = q_bf;                    // alias: q dead after attention

    transpose_cast_img<<<dim3(16, 8, 16), 256, 0, stream>>>(img, img_bf);
    cast_audio<<<dim3(1024), 256, 0, stream>>>(audio, aud_bf);
    transpose_cast_w<<<dim3(8, 8, 4), 256, 0, stream>>>(Wq, Wk, Wv, Wo, wT);

    // Q projection: M=16384, N=512
    gemm_bf16_mfma<<<dim3(128, 4), 256, 0, stream>>>(img_bf, wT, bq, q_bf);
    // K|V fused: M=4096, N=1024 (Bt rows 0..511 = Wk^T, 512..1023 = Wv^T)
    gemm_kv_mfma<<<dim3(32, 8), 256, 0, stream>>>(aud_bf, wT + 262144, bk, bv, kh_bf, vt_bf);
    // MFMA attention
    attn_mfma<<<dim3(B_SZ * N_HEADS, HW / 64), 256, 0, stream>>>(q_bf, kh_bf, vt_bf, a_bf);
    // Output projection: M=16384, N=512
    gemm_bf16_mfma<<<dim3(128, 4), 256, 0, stream>>>(a_bf, wT + 3 * 262144, bo, p_bf);
    // Residual + LN + transpose
    ln_kernel<<<dim3(32, 16), 256, 0, stream>>>(p_bf, img_bf, gamma, beta, (float*)d_out);
}